// Round 6
// baseline (14126.527 us; speedup 1.0000x reference)
//
#include <hip/hip_runtime.h>
#include <hip/hip_bf16.h>
#include <cstdint>
#include <cstddef>

// Problem: S=4096, I=1024, H=1024. 4H=4096. ALL tensors fp32 (per reference).
// out (fp32): all_hidden (4096 x 2048) then final_h (2048), flat.

typedef __attribute__((ext_vector_type(8))) short short8;
typedef __attribute__((ext_vector_type(4))) short short4v;
typedef __attribute__((ext_vector_type(4))) float float4v;
typedef unsigned long long ull;

__device__ __forceinline__ float bf2f(unsigned short u) {
    return __uint_as_float(((unsigned int)u) << 16);
}
__device__ __forceinline__ unsigned short f2bf(float f) {
    __hip_bfloat16 h = __float2bfloat16(f);  // RNE
    return *reinterpret_cast<unsigned short*>(&h);
}
__device__ __forceinline__ float sigm(float x) {
    return 1.f / (1.f + __expf(-x));
}
__device__ __forceinline__ float tanh_fast(float x) {
    return 1.f - 2.f / (__expf(2.f * x) + 1.f);   // exact at +-inf, ~1e-6 rel
}

// ---------------------------------------------------------------------------
// Kernel A: x_proj[d][t][j] = b[d][j] + sum_k inp[t][k] * W[d][j][1024+k]
// fp32 -> bf16 LDS tiles -> mfma_f32_16x16x32_bf16 -> fp32 x_proj.
// ---------------------------------------------------------------------------
__global__ __launch_bounds__(256)
void xproj_gemm(const float* __restrict__ inp,
                const float* __restrict__ fw,
                const float* __restrict__ fb,
                const float* __restrict__ bw,
                const float* __restrict__ bb,
                float* __restrict__ xp)
{
    const int d  = blockIdx.z;
    const float* W = d ? bw : fw;
    const float* B = d ? bb : fb;
    const int t0 = blockIdx.y * 128;
    const int n0 = blockIdx.x * 128;

    __shared__ __align__(16) short Ash[128 * 32];
    __shared__ __align__(16) short Bsh[128 * 32];

    const int tid  = threadIdx.x;
    const int lane = tid & 63;
    const int wave = tid >> 6;
    const int wm = (wave & 1) * 64;
    const int wn = (wave >> 1) * 64;
    const int quad = lane >> 4;
    const int l15  = lane & 15;

    float4v acc[4][4];
    float4v zero4 = {0.f, 0.f, 0.f, 0.f};
#pragma unroll
    for (int mi = 0; mi < 4; mi++)
#pragma unroll
        for (int ni = 0; ni < 4; ni++) acc[mi][ni] = zero4;

    for (int k0 = 0; k0 < 1024; k0 += 32) {
#pragma unroll
        for (int s = 0; s < 4; s++) {
            int c   = tid + s * 256;       // 0..1023
            int row = c >> 3;              // 0..127
            int ko  = (c & 7) * 4;         // 0..28
            float4v va = *(const float4v*)&inp[(size_t)(t0 + row) * 1024 + k0 + ko];
            float4v vb = *(const float4v*)&W[(size_t)(n0 + row) * 2048 + 1024 + k0 + ko];
            short4v sa, sb;
#pragma unroll
            for (int e = 0; e < 4; e++) {
                sa[e] = (short)f2bf(va[e]);
                sb[e] = (short)f2bf(vb[e]);
            }
            *(short4v*)&Ash[row * 32 + ko] = sa;
            *(short4v*)&Bsh[row * 32 + ko] = sb;
        }
        __syncthreads();

        short8 af[4], bfr[4];
#pragma unroll
        for (int mi = 0; mi < 4; mi++)
            af[mi] = *(const short8*)&Ash[(wm + mi * 16 + l15) * 32 + quad * 8];
#pragma unroll
        for (int ni = 0; ni < 4; ni++)
            bfr[ni] = *(const short8*)&Bsh[(wn + ni * 16 + l15) * 32 + quad * 8];

#pragma unroll
        for (int mi = 0; mi < 4; mi++)
#pragma unroll
            for (int ni = 0; ni < 4; ni++)
                acc[mi][ni] = __builtin_amdgcn_mfma_f32_16x16x32_bf16(
                    af[mi], bfr[ni], acc[mi][ni], 0, 0, 0);
        __syncthreads();
    }

#pragma unroll
    for (int ni = 0; ni < 4; ni++) {
        int gc = n0 + wn + ni * 16 + l15;
        float bias = B[gc];
#pragma unroll
        for (int mi = 0; mi < 4; mi++) {
#pragma unroll
            for (int r = 0; r < 4; r++) {
                int gr = t0 + wm + mi * 16 + quad * 4 + r;
                xp[((size_t)d * 4096 + gr) * 4096 + gc] = acc[mi][ni][r] + bias;
            }
        }
    }
}

// ---------------------------------------------------------------------------
// Kernel B: persistent bidirectional LSTM recurrence, fence-free tagged sync.
//
// Sync scheme (round 3/4): hq is uint32[dir][2][1024]; each word = fp32 h
// with its 2 LOW MANTISSA BITS replaced by (step & 3). Parity double-buffer
// means a polled slot only ever holds step t or t-2 -> 2-bit tag fully
// disambiguates; perturbation <=3 ulp. memset-0 init == tag 0 == h^0.
// Poll: ONE 8B relaxed agent-scope atomic load covers 2 adjacent units.
// Publish: ONE 8B atomic store covers the same 2 units (producer/consumer
// words are 1:1).
//
// Round-5 structure (critical-path collapse): wave w of a block owns units
// {u0+2w, u0+2w+1} END-TO-END. Lane l: col-chunk cc=l>>3, row rl2=l&7
// (rl2 = gate*2 + unit-parity). Each lane does a 128-col partial of its
// z-row; a 3-step shfl_xor tree (masks 8/16/32) reduces over the 8 cc
// groups; gates are computed in-wave; the wave publishes its 8B pair
// immediately. This DELETES the S2 barrier, the psum LDS array, and the
// serial wave-0 epilogue from the per-step critical path. One
// __syncthreads per step remains (after the h LDS fill: every wave reads
// all 1024 h). hsh is parity-double-buffered (no trailing barrier) and
// chunk-padded to 132 floats so the 8 broadcast addresses of each
// ds_read_b128 hit 8 distinct bank-quads (conflict-free).
//
// Safety: publish(t+1) by wave w requires w passed barrier(t), which
// requires ALL the block's polls of step t succeeded; overwrite at t+2
// transitively requires every block consumed step t (each block polls the
// full h vector). Tags cycle mod 4; a slot polled for step s can only hold
// s or s-2 (the consumer itself verified s-2 in that slot two steps ago).
// ---------------------------------------------------------------------------
template <int FUSED>
__global__ __launch_bounds__(512, 2)
void lstm_rec(const float* __restrict__ fw,
              const float* __restrict__ bw,
              const float* __restrict__ fb,
              const float* __restrict__ bb,
              const float* __restrict__ inp,
              const float* __restrict__ xp,
              unsigned int* __restrict__ hq,     // [dir][2][1024] tagged f32
              float* __restrict__ out)
{
    const int dir  = blockIdx.x & 1;
    const int slot = blockIdx.x >> 1;          // 0..63
    const int u0   = slot * 16;                // 16 units per block
    const int T    = threadIdx.x;              // 0..511
    const int wv   = T >> 6;                   // wave 0..7 -> units u0+2wv,+1
    const int l    = T & 63;
    const int cc   = l >> 3;                   // col chunk 0..7
    const int rl2  = l & 7;                    // row-in-wave 0..7
    const int p    = rl2 & 1;                  // unit parity
    const int g    = rl2 >> 1;                 // gate 0..3 (f,i,g,o)
    const int j    = g * 1024 + u0 + 2 * wv + p;   // global z-row
    const float* W = dir ? bw : fw;

    // chunk-padded, parity-double-buffered h (and x) staging
    __shared__ __align__(16) float hsh[2][8 * 132];
    __shared__ __align__(16) float xsh[2][8 * 132];   // FUSED only

    // Wh weights (cols [cc*128,+128) of row j) -> regs
    float w[128];
    {
        const float* wr = W + (size_t)j * 2048 + cc * 128;
#pragma unroll
        for (int i = 0; i < 32; i++)
            *(float4v*)&w[4 * i] = *(const float4v*)&wr[4 * i];
    }

    // FUSED: Wx packed bf16 + per-row bias (cc==0 lanes carry the bias)
    unsigned int w2[64];
    float brow = 0.f;
    if (FUSED) {
        const float* wr2 = W + (size_t)j * 2048 + 1024 + cc * 128;
#pragma unroll
        for (int i = 0; i < 32; i++) {
            float4v v = *(const float4v*)&wr2[4 * i];
            w2[2 * i]     = (unsigned int)f2bf(v[0]) | ((unsigned int)f2bf(v[1]) << 16);
            w2[2 * i + 1] = (unsigned int)f2bf(v[2]) | ((unsigned int)f2bf(v[3]) << 16);
        }
        if (cc == 0)
            brow = (dir ? bb : fb)[j];
    }

    unsigned int* hqd = hq + dir * 2048;
    float c = 0.f;   // cell state for unit u0+2wv+(l&1) (lanes 0,1 are live)

    for (int t = 0; t < 4096; t++) {
        const int tr  = dir ? (4095 - t) : t;
        const int par = t & 1;

        // independent global loads first (long latency, off critical path)
        float xv = 0.f;
        float2 iv;
        if (FUSED) {
            iv = ((const float2*)&inp[(size_t)tr * 1024])[T];
        } else if (cc == 0) {
            xv = xp[((size_t)dir * 4096 + tr) * 4096 + j];
        }

        // poll pair T (units 2T,2T+1) with ONE 8B load; 2-bit embedded tags
        {
            const ull tag2 = ((ull)((unsigned)t & 3u)) * 0x100000001ull;
            ull* q0 = (ull*)(hqd + par * 1024 + 2 * T);
            ull w0 = __hip_atomic_load(q0, __ATOMIC_RELAXED, __HIP_MEMORY_SCOPE_AGENT);
            while ((w0 & 0x0000000300000003ull) != tag2) {
                __builtin_amdgcn_s_sleep(1);   // ~64 cy backoff, decongest fabric
                w0 = __hip_atomic_load(q0, __ATOMIC_RELAXED, __HIP_MEMORY_SCOPE_AGENT);
            }
            const int k = 2 * T;               // global h index of first word
            *(ull*)&hsh[par][(k >> 7) * 132 + (k & 127)] = w0;   // raw bits
            if (FUSED)
                *(float2*)&xsh[par][(k >> 7) * 132 + (k & 127)] = iv;
        }
        __syncthreads();   // S1: full h (and x) staged; only barrier per step

        // z partial: 128 reg-resident fp32 MACs (8-way broadcast LDS reads,
        // conflict-free via the 132-float chunk stride)
        float a0 = 0.f, a1 = 0.f, a2 = 0.f, a3 = 0.f;
        const float4v* h4 = (const float4v*)&hsh[par][cc * 132];
#pragma unroll
        for (int i = 0; i < 32; i++) {
            float4v hv = h4[i];
            a0 = __builtin_fmaf(w[4 * i + 0], hv.x, a0);
            a1 = __builtin_fmaf(w[4 * i + 1], hv.y, a1);
            a2 = __builtin_fmaf(w[4 * i + 2], hv.z, a2);
            a3 = __builtin_fmaf(w[4 * i + 3], hv.w, a3);
        }
        if (FUSED) {
            const float* xs = &xsh[par][cc * 132];
#pragma unroll
            for (int i = 0; i < 64; i++) {
                unsigned int dv = w2[i];
                a0 = __builtin_fmaf(bf2f((unsigned short)(dv & 0xffffu)),
                                    xs[2 * i], a0);
                a1 = __builtin_fmaf(bf2f((unsigned short)(dv >> 16)),
                                    xs[2 * i + 1], a1);
            }
        }
        float s = ((a0 + a1) + (a2 + a3)) + xv;   // xv = xp (or 0)
        if (FUSED && cc == 0) s += brow;

        // reduce over the 8 col-chunks: lanes {l, l^8, l^16, l^32} share rl2
        s += __shfl_xor(s, 8);
        s += __shfl_xor(s, 16);
        s += __shfl_xor(s, 32);
        // every lane now holds full z for row rl2 = l&7

        // gates for unit parity p=l&1 (rows p, 2+p, 4+p, 6+p = f,i,g,o)
        float z0 = __shfl(s, p);
        float z1 = __shfl(s, 2 + p);
        float z2 = __shfl(s, 4 + p);
        float z3 = __shfl(s, 6 + p);
        c = sigm(z0) * c + sigm(z1) * tanh_fast(z2);
        float hv = sigm(z3) * tanh_fast(c);

        // pack the wave's 2 units; lane 0 publishes one 8B tagged word FIRST,
        // then the out stores (publish is the global critical path)
        unsigned int hb = (__float_as_uint(hv) & ~3u) | ((unsigned)(t + 1) & 3u);
        unsigned int hb1 = __shfl(hb, 1);
        float hv1 = __shfl(hv, 1);
        if (l == 0) {
            ull pw = ((ull)hb1 << 32) | (ull)hb;
            __hip_atomic_store((ull*)&hqd[((t + 1) & 1) * 1024 + u0 + 2 * wv], pw,
                               __ATOMIC_RELAXED, __HIP_MEMORY_SCOPE_AGENT);
            float2 o2 = {hv, hv1};
            *(float2*)&out[(size_t)tr * 2048 + dir * 1024 + u0 + 2 * wv] = o2;
            if (t == 4095)   // final_h: fwd = hs[4095], bwd = hs[0]
                *(float2*)&out[(size_t)4096 * 2048 + dir * 1024 + u0 + 2 * wv] = o2;
        }
    }
}

// ---------------------------------------------------------------------------
extern "C" void kernel_launch(void* const* d_in, const int* in_sizes, int n_in,
                              void* d_out, int out_size, void* d_ws, size_t ws_size,
                              hipStream_t stream)
{
    const float* inp = (const float*)d_in[0];
    const float* fw  = (const float*)d_in[1];
    const float* fb  = (const float*)d_in[2];
    const float* bw  = (const float*)d_in[3];
    const float* bb  = (const float*)d_in[4];

    char* ws = (char*)d_ws;
    unsigned int* hq = (unsigned int*)ws;          // 16 KB: [dir][2][1024] x 4B
    float* xp = (float*)(ws + 32768);              // x_proj: 2 x 4096 x 4096 fp32

    const size_t XP_BYTES = 2ull * 4096 * 4096 * 4;   // 134.2 MB
    const int have_xp = (ws_size >= 32768 + XP_BYTES);

    hipMemsetAsync(ws, 0, 16384, stream);   // tag 0 / h=0 == step-0 state

    float* outp = (float*)d_out;
    if (have_xp) {
        dim3 gg(32, 32, 2);
        xproj_gemm<<<gg, 256, 0, stream>>>(inp, fw, fb, bw, bb, xp);
        lstm_rec<0><<<dim3(128), 512, 0, stream>>>(fw, bw, fb, bb, inp, xp,
                                                   hq, outp);
    } else {
        lstm_rec<1><<<dim3(128), 512, 0, stream>>>(fw, bw, fb, bb, inp, nullptr,
                                                   hq, outp);
    }
}

// Round 7
// 9823.538 us; speedup vs baseline: 1.4380x; 1.4380x over previous
//
#include <hip/hip_runtime.h>
#include <hip/hip_bf16.h>
#include <cstdint>
#include <cstddef>

// Problem: S=4096, I=1024, H=1024. 4H=4096. ALL tensors fp32 (per reference).
// out (fp32): all_hidden (4096 x 2048) then final_h (2048), flat.

typedef __attribute__((ext_vector_type(8))) short short8;
typedef __attribute__((ext_vector_type(4))) short short4v;
typedef __attribute__((ext_vector_type(4))) float float4v;
typedef unsigned long long ull;

__device__ __forceinline__ float bf2f(unsigned short u) {
    return __uint_as_float(((unsigned int)u) << 16);
}
__device__ __forceinline__ unsigned short f2bf(float f) {
    __hip_bfloat16 h = __float2bfloat16(f);  // RNE
    return *reinterpret_cast<unsigned short*>(&h);
}
__device__ __forceinline__ float sigm(float x) {
    return 1.f / (1.f + __expf(-x));
}
__device__ __forceinline__ float tanh_fast(float x) {
    return 1.f - 2.f / (__expf(2.f * x) + 1.f);   // exact at +-inf, ~1e-6 rel
}

// ---------------------------------------------------------------------------
// Kernel A: x_proj[d][t][j] = b[d][j] + sum_k inp[t][k] * W[d][j][1024+k]
// fp32 -> bf16 LDS tiles -> mfma_f32_16x16x32_bf16 -> fp32 x_proj.
// ---------------------------------------------------------------------------
__global__ __launch_bounds__(256)
void xproj_gemm(const float* __restrict__ inp,
                const float* __restrict__ fw,
                const float* __restrict__ fb,
                const float* __restrict__ bw,
                const float* __restrict__ bb,
                float* __restrict__ xp)
{
    const int d  = blockIdx.z;
    const float* W = d ? bw : fw;
    const float* B = d ? bb : fb;
    const int t0 = blockIdx.y * 128;
    const int n0 = blockIdx.x * 128;

    __shared__ __align__(16) short Ash[128 * 32];
    __shared__ __align__(16) short Bsh[128 * 32];

    const int tid  = threadIdx.x;
    const int lane = tid & 63;
    const int wave = tid >> 6;
    const int wm = (wave & 1) * 64;
    const int wn = (wave >> 1) * 64;
    const int quad = lane >> 4;
    const int l15  = lane & 15;

    float4v acc[4][4];
    float4v zero4 = {0.f, 0.f, 0.f, 0.f};
#pragma unroll
    for (int mi = 0; mi < 4; mi++)
#pragma unroll
        for (int ni = 0; ni < 4; ni++) acc[mi][ni] = zero4;

    for (int k0 = 0; k0 < 1024; k0 += 32) {
#pragma unroll
        for (int s = 0; s < 4; s++) {
            int c   = tid + s * 256;       // 0..1023
            int row = c >> 3;              // 0..127
            int ko  = (c & 7) * 4;         // 0..28
            float4v va = *(const float4v*)&inp[(size_t)(t0 + row) * 1024 + k0 + ko];
            float4v vb = *(const float4v*)&W[(size_t)(n0 + row) * 2048 + 1024 + k0 + ko];
            short4v sa, sb;
#pragma unroll
            for (int e = 0; e < 4; e++) {
                sa[e] = (short)f2bf(va[e]);
                sb[e] = (short)f2bf(vb[e]);
            }
            *(short4v*)&Ash[row * 32 + ko] = sa;
            *(short4v*)&Bsh[row * 32 + ko] = sb;
        }
        __syncthreads();

        short8 af[4], bfr[4];
#pragma unroll
        for (int mi = 0; mi < 4; mi++)
            af[mi] = *(const short8*)&Ash[(wm + mi * 16 + l15) * 32 + quad * 8];
#pragma unroll
        for (int ni = 0; ni < 4; ni++)
            bfr[ni] = *(const short8*)&Bsh[(wn + ni * 16 + l15) * 32 + quad * 8];

#pragma unroll
        for (int mi = 0; mi < 4; mi++)
#pragma unroll
            for (int ni = 0; ni < 4; ni++)
                acc[mi][ni] = __builtin_amdgcn_mfma_f32_16x16x32_bf16(
                    af[mi], bfr[ni], acc[mi][ni], 0, 0, 0);
        __syncthreads();
    }

#pragma unroll
    for (int ni = 0; ni < 4; ni++) {
        int gc = n0 + wn + ni * 16 + l15;
        float bias = B[gc];
#pragma unroll
        for (int mi = 0; mi < 4; mi++) {
#pragma unroll
            for (int r = 0; r < 4; r++) {
                int gr = t0 + wm + mi * 16 + quad * 4 + r;
                xp[((size_t)d * 4096 + gr) * 4096 + gc] = acc[mi][ni][r] + bias;
            }
        }
    }
}

// ---------------------------------------------------------------------------
// Kernel B: persistent bidirectional LSTM recurrence, fence-free tagged sync.
//
// Sync scheme: hq is uint32[dir][2][1024]; each word = fp32 h with its 2 LOW
// MANTISSA BITS replaced by (step & 3). Parity double-buffer means a polled
// slot only ever holds step t or t-2 -> 2-bit tag fully disambiguates;
// perturbation <=3 ulp. memset-0 init == tag 0 == h^0.
// Poll: ONE 8B relaxed agent-scope atomic load covers 2 adjacent units.
// Publish: 16x 4B atomic stores from one wave (coalesced line).
//
// Round-6 change (detect-period attack): 4-deep software-pipelined spin.
// The old spin (load -> vmcnt(0) full-RTT wait -> check -> s_sleep(64))
// re-checks only every ~RTT+64 cy, so a publish landing mid-period waits
// ~0.5 period extra. Keeping 4 tagged loads in flight and checking the
// OLDEST (compiler emits vmcnt(3)) self-paces checks at ~RTT/4. Per-4B
// self-validating tags make same-address completion reordering harmless
// (only tag==t is acted upon; stale values just spin). r4 evidence
// (halving poll ops left duration flat) showed polls are not
// throughput-bound -> higher spin rate is safe; depth caps in-flight.
//
// Structure (r3/r4, best measured): 128 blocks x 512 threads, 16 units per
// block. NO pre-FMA barrier: wave w's hsh segment [128w,+128) is written
// and read only by itself (s_waitcnt lgkmcnt(0) orders it); each wave
// enters FMA on its OWN detect; coupling deferred to S2 where FMA time
// absorbs straggler spread. (r5's pre-FMA full barrier regressed 60%.)
//
// Safety: a block publishes t+1 only after S2(t), which its tag-t polls
// precede; publish of t+2 (overwriting step-t slots) transitively requires
// every block's step-t polls completed. No clobber of live words.
// ---------------------------------------------------------------------------
template <int FUSED>
__global__ __launch_bounds__(512, 2)
void lstm_rec(const float* __restrict__ fw,
              const float* __restrict__ bw,
              const float* __restrict__ fb,
              const float* __restrict__ bb,
              const float* __restrict__ inp,
              const float* __restrict__ xp,
              unsigned int* __restrict__ hq,     // [dir][2][1024] tagged f32
              float* __restrict__ out)
{
    const int dir  = blockIdx.x & 1;
    const int slot = blockIdx.x >> 1;          // 0..63
    const int u0   = slot * 16;                // 16 units per block
    const int T    = threadIdx.x;              // 0..511
    const int rl   = T & 63;                   // z-row-local 0..63
    const int gate = rl >> 4;
    const int ul   = rl & 15;
    const int chunk = T >> 6;                  // wave id 0..7 (128-col chunk)
    const int j    = gate * 1024 + u0 + ul;    // global z-row
    const float* W = dir ? bw : fw;

    __shared__ __align__(16) float hsh[1024];
    __shared__ __align__(16) float xsh[1024];     // FUSED only
    __shared__ float psum[2][64 * 9];             // per-parity partials

    // Wh weights (cols [chunk*128,+128) of row j) -> regs
    float w[128];
    {
        const float* wr = W + (size_t)j * 2048 + chunk * 128;
#pragma unroll
        for (int i = 0; i < 32; i++)
            *(float4v*)&w[4 * i] = *(const float4v*)&wr[4 * i];
    }

    // FUSED: Wx packed bf16 + per-row bias
    unsigned int w2[64];
    float brow = 0.f;
    if (FUSED) {
        const float* wr2 = W + (size_t)j * 2048 + 1024 + chunk * 128;
#pragma unroll
        for (int i = 0; i < 32; i++) {
            float4v v = *(const float4v*)&wr2[4 * i];
            w2[2 * i]     = (unsigned int)f2bf(v[0]) | ((unsigned int)f2bf(v[1]) << 16);
            w2[2 * i + 1] = (unsigned int)f2bf(v[2]) | ((unsigned int)f2bf(v[3]) << 16);
        }
        if (T < 64)
            brow = (dir ? bb : fb)[(T >> 4) * 1024 + u0 + (T & 15)];
    }

    unsigned int* hqd = hq + dir * 2048;
    float c = 0.f;   // cell state for unit u0+T (threads T<16)

    for (int t = 0; t < 4096; t++) {
        const int tr  = dir ? (4095 - t) : t;
        const int par = t & 1;

        // independent global loads first (long latency, off critical path)
        float xv = 0.f;
        float2 iv;
        if (FUSED) {
            iv = ((const float2*)&inp[(size_t)tr * 1024])[T];
        } else if (T < 64) {
            xv = xp[((size_t)dir * 4096 + tr) * 4096 + j];
        }

        // poll pair T (units 2T,2T+1): 4-deep pipelined spin, check oldest.
        {
            const ull tagm = 0x0000000300000003ull;
            const ull tag2 = ((ull)((unsigned)t & 3u)) * 0x100000001ull;
            ull* q0 = (ull*)(hqd + par * 1024 + 2 * T);
            ull r0 = __hip_atomic_load(q0, __ATOMIC_RELAXED, __HIP_MEMORY_SCOPE_AGENT);
            ull r1 = __hip_atomic_load(q0, __ATOMIC_RELAXED, __HIP_MEMORY_SCOPE_AGENT);
            ull r2 = __hip_atomic_load(q0, __ATOMIC_RELAXED, __HIP_MEMORY_SCOPE_AGENT);
            ull r3 = __hip_atomic_load(q0, __ATOMIC_RELAXED, __HIP_MEMORY_SCOPE_AGENT);
            ull got;
            for (;;) {
                if ((r0 & tagm) == tag2) { got = r0; break; }
                r0 = __hip_atomic_load(q0, __ATOMIC_RELAXED, __HIP_MEMORY_SCOPE_AGENT);
                if ((r1 & tagm) == tag2) { got = r1; break; }
                r1 = __hip_atomic_load(q0, __ATOMIC_RELAXED, __HIP_MEMORY_SCOPE_AGENT);
                if ((r2 & tagm) == tag2) { got = r2; break; }
                r2 = __hip_atomic_load(q0, __ATOMIC_RELAXED, __HIP_MEMORY_SCOPE_AGENT);
                if ((r3 & tagm) == tag2) { got = r3; break; }
                r3 = __hip_atomic_load(q0, __ATOMIC_RELAXED, __HIP_MEMORY_SCOPE_AGENT);
            }
            *(ull*)&hsh[2 * T] = got;   // raw bits; tag bits are <=3 ulp noise
        }
        if (FUSED) {
            xsh[2 * T]     = iv.x;
            xsh[2 * T + 1] = iv.y;
        }
        // NO block barrier: hsh/xsh segment [chunk*128,+128) is private to
        // this wave. Order the same-wave LDS write->read explicitly.
        asm volatile("s_waitcnt lgkmcnt(0)" ::: "memory");

        // z partial: 128 reg-resident fp32 MACs (wave-broadcast LDS reads)
        float a0 = 0.f, a1 = 0.f, a2 = 0.f, a3 = 0.f;
        const float4v* h4 = (const float4v*)&hsh[chunk * 128];
#pragma unroll
        for (int i = 0; i < 32; i++) {
            float4v hv = h4[i];
            a0 = __builtin_fmaf(w[4 * i + 0], hv.x, a0);
            a1 = __builtin_fmaf(w[4 * i + 1], hv.y, a1);
            a2 = __builtin_fmaf(w[4 * i + 2], hv.z, a2);
            a3 = __builtin_fmaf(w[4 * i + 3], hv.w, a3);
        }
        if (FUSED) {
            const float* xs = &xsh[chunk * 128];
#pragma unroll
            for (int i = 0; i < 64; i++) {
                unsigned int dv = w2[i];
                a0 = __builtin_fmaf(bf2f((unsigned short)(dv & 0xffffu)),
                                    xs[2 * i], a0);
                a1 = __builtin_fmaf(bf2f((unsigned short)(dv >> 16)),
                                    xs[2 * i + 1], a1);
            }
        }
        psum[par][rl * 9 + chunk] = (a0 + a1) + (a2 + a3);
        __syncthreads();   // S2: psum ready

        // epilogue on wave 0: 64 row-reducers -> shfl gather -> 16 gate lanes.
        // Publish FIRST (critical path), then the out stores.
        if (T < 64) {
            float s = FUSED ? brow : xv;
            const float* pp = &psum[par][T * 9];
#pragma unroll
            for (int cc = 0; cc < 8; cc++) s += pp[cc];
            const int u = T & 15;
            float z0 = __shfl(s, u);           // gate f: row u
            float z1 = __shfl(s, u + 16);      // gate i
            float z2 = __shfl(s, u + 32);      // gate g
            float z3 = __shfl(s, u + 48);      // gate o
            if (T < 16) {
                c = sigm(z0) * c + sigm(z1) * tanh_fast(z2);
                float hv = sigm(z3) * tanh_fast(c);
                unsigned int hb = (__float_as_uint(hv) & ~3u)
                                | ((unsigned)(t + 1) & 3u);
                __hip_atomic_store(&hqd[((t + 1) & 1) * 1024 + u0 + T], hb,
                                   __ATOMIC_RELAXED, __HIP_MEMORY_SCOPE_AGENT);
                out[(size_t)tr * 2048 + dir * 1024 + u0 + T] = hv;
                if (t == 4095)   // final_h: fwd = hs[4095], bwd = hs[0]
                    out[(size_t)4096 * 2048 + dir * 1024 + u0 + T] = hv;
            }
        }
    }
}

// ---------------------------------------------------------------------------
extern "C" void kernel_launch(void* const* d_in, const int* in_sizes, int n_in,
                              void* d_out, int out_size, void* d_ws, size_t ws_size,
                              hipStream_t stream)
{
    const float* inp = (const float*)d_in[0];
    const float* fw  = (const float*)d_in[1];
    const float* fb  = (const float*)d_in[2];
    const float* bw  = (const float*)d_in[3];
    const float* bb  = (const float*)d_in[4];

    char* ws = (char*)d_ws;
    unsigned int* hq = (unsigned int*)ws;          // 16 KB: [dir][2][1024] x 4B
    float* xp = (float*)(ws + 32768);              // x_proj: 2 x 4096 x 4096 fp32

    const size_t XP_BYTES = 2ull * 4096 * 4096 * 4;   // 134.2 MB
    const int have_xp = (ws_size >= 32768 + XP_BYTES);

    hipMemsetAsync(ws, 0, 16384, stream);   // tag 0 / h=0 == step-0 state

    float* outp = (float*)d_out;
    if (have_xp) {
        dim3 gg(32, 32, 2);
        xproj_gemm<<<gg, 256, 0, stream>>>(inp, fw, fb, bw, bb, xp);
        lstm_rec<0><<<dim3(128), 512, 0, stream>>>(fw, bw, fb, bb, inp, xp,
                                                   hq, outp);
    } else {
        lstm_rec<1><<<dim3(128), 512, 0, stream>>>(fw, bw, fb, bb, inp, nullptr,
                                                   hq, outp);
    }
}